// Round 1
// 100.090 us; speedup vs baseline: 1.0406x; 1.0406x over previous
//
#include <hip/hip_runtime.h>

// AdaptiveHighPassFilter: conv3x3(64->9, zero-pad) -> softmax(taps) -> hamming
// renorm -> CARAFE(3x3, reflect) -> 2x - lowpass.
//
// R7 = R6 with the manual RNE bf16 pack (f2bf/pkbf, ~10 VALU ops per packed
// pair) replaced by gfx950's v_cvt_pk_bf16_f32 (1 VALU op per pair, RNE,
// inline asm -- no builtin exists). Staging pack cost drops ~10x; total
// kernel VALU ~-35%. Everything else identical to R6:
//  - carafe computed from the conv's own B-fragment REGISTERS (they hold the
//    9 shifted neighborhoods already); mask broadcast via 5 shuffles. No
//    smask LDS, no carafe ds_reads, one barrier total.
//  - weights pre-fragmented into d_ws by a tiny prep kernel -> main kernel
//    A-frags are 18 coalesced dwordx4 loads.
//  - 16x8 tiles, 128-thr blocks, 1024 blocks, LDS 25.9KB.
//  - staging: 8ch x 4pos transposed slots, ds_write_b128 (15 writes/thread).
//  - plain stores (R4 nontemporal inflated WRITE 1.5x); keep XCD swizzle
//    (R4 evidence: FETCH 57->19MB).

typedef __attribute__((ext_vector_type(8))) short short8;
typedef __attribute__((ext_vector_type(4))) float floatx4;
typedef __attribute__((ext_vector_type(4))) unsigned uint4v;
typedef __attribute__((ext_vector_type(2))) float float2v;

#define IH 128
#define IW 128
#define CCH 64
#define TSX 16
#define TSY 8
#define TPX 18
#define TPY 10
#define CSH 72   // shorts per position: 144B row, 16B-aligned, bank stride 4

__device__ __forceinline__ unsigned short f2bf(float f) {
    unsigned u = __float_as_uint(f);
    u += 0x7FFFu + ((u >> 16) & 1u);     // round-to-nearest-even
    return (unsigned short)(u >> 16);
}
// 1-instruction RNE pack of two f32 -> packed bf16x2 (lo = a, hi = b)
__device__ __forceinline__ unsigned cvtpk(float a, float b) {
    unsigned r;
    asm("v_cvt_pk_bf16_f32 %0, %1, %2" : "=v"(r) : "v"(a), "v"(b));
    return r;
}
__device__ __forceinline__ float2v unpk(unsigned u) {
    float2v r;
    r.x = __uint_as_float(u << 16);
    r.y = __uint_as_float(u & 0xFFFF0000u);
    return r;
}

// ---- prep: W[9][64][3][3] f32 -> bf16 A-fragments ws[s][lane][8shorts]
__global__ void ahpf_prep(const float* __restrict__ Wg,
                          unsigned short* __restrict__ wsp)
{
    const int i = blockIdx.x * 256 + threadIdx.x;   // 0..1151
    if (i >= 18 * 64) return;
    const int s = i >> 6, l = i & 63;
    const int fm = l & 15, fq = l >> 4;
    const int tap = s >> 1, cb = (s & 1) * 32 + fq * 8;
    short8 v = (short8)0;
    if (fm < 9) {
#pragma unroll
        for (int jj = 0; jj < 8; ++jj)
            v[jj] = (short)f2bf(Wg[fm * 576 + (cb + jj) * 9 + tap]);
    }
    ((short8*)wsp)[i] = v;
}

template <bool USE_WS>
__global__ __launch_bounds__(128, 2) void ahpf_kernel(
    const float* __restrict__ x, const float* __restrict__ Wg,
    const float* __restrict__ bias, float* __restrict__ out,
    const unsigned short* __restrict__ wsp)
{
    __shared__ __align__(16) unsigned short sx[TPY * TPX * CSH];  // 25,920 B

    const int tid  = threadIdx.x;
    const int lane = tid & 63;
    const int wv   = tid >> 6;

    // XCD swizzle: XCD k gets the 128 tiles of image k
    const unsigned flat = blockIdx.x + 8u * (blockIdx.y + 16u * blockIdx.z);
    const unsigned nid  = (flat & 7u) * 128u + (flat >> 3);
    const int bx = nid & 7, by = (nid >> 3) & 15, bz = nid >> 7;

    const int ty0 = by * TSY;
    const int tx0 = bx * TSX;
    const size_t hw = (size_t)IH * IW;
    const float* xb = x + (size_t)bz * CCH * hw;

    const int fm = lane & 15;   // conv: pixel col n / A row m
    const int fq = lane >> 4;

    // ---- A-fragments: 18 coalesced b128 loads from prep ws (or gather fallback)
    short8 afr[18];
    if (USE_WS) {
        const short8* wf = (const short8*)wsp;
#pragma unroll
        for (int s = 0; s < 18; ++s) afr[s] = wf[s * 64 + lane];
    } else {
#pragma unroll
        for (int s = 0; s < 18; ++s) {
            short8 a = (short8)0;
            if (fm < 9) {
                const int tap = s >> 1, cb = (s & 1) * 32 + fq * 8;
                const float* wp = Wg + fm * 576 + tap;
#pragma unroll
                for (int jj = 0; jj < 8; ++jj)
                    a[jj] = (short)f2bf(wp[(cb + jj) * 9]);
            }
            afr[s] = a;
        }
    }
    float bq[4];
#pragma unroll
    for (int r = 0; r < 4; ++r) {
        const int t = fq * 4 + r;
        bq[r] = (t < 9) ? bias[t] : 0.0f;
    }

    // ---- stage reflect-padded tile bf16 [pos][c]; slots = 8ch x 4pos
    {
        int gx0 = tx0 - 4;
        if (gx0 < 0) gx0 = 0;
        if (gx0 > IW - 24) gx0 = IW - 24;
        const bool xlo = (bx == 0), xhi = (bx == 7);
        const int cg8 = tid & 7;                 // fixed per thread
#pragma unroll
        for (int it = 0; it < 4; ++it) {
            const int s = it * 128 + tid;        // 480 slots total
            if (s >= 480) break;
            const int u = s >> 3;                // 0..59
            const int y = u / 6, xg = u - 6 * y;
            int gy = ty0 + y - 1;
            gy = gy < 0 ? -gy : (gy >= IH ? 2 * IH - 2 - gy : gy);
            const float* src = xb + (size_t)(cg8 * 8) * hw
                             + (size_t)gy * IW + gx0 + 4 * xg;
            float4 v[8];
#pragma unroll
            for (int jj = 0; jj < 8; ++jj)
                v[jj] = *(const float4*)(src + (size_t)jj * hw);
            const int xbase = gx0 + 4 * xg - tx0 + 1;
#pragma unroll
            for (int e = 0; e < 4; ++e) {
                const float fe[8] = {
                    ((const float*)&v[0])[e], ((const float*)&v[1])[e],
                    ((const float*)&v[2])[e], ((const float*)&v[3])[e],
                    ((const float*)&v[4])[e], ((const float*)&v[5])[e],
                    ((const float*)&v[6])[e], ((const float*)&v[7])[e]};
                uint4v pk;
                pk.x = cvtpk(fe[0], fe[1]); pk.y = cvtpk(fe[2], fe[3]);
                pk.z = cvtpk(fe[4], fe[5]); pk.w = cvtpk(fe[6], fe[7]);
                const int gxe = gx0 + 4 * xg + e;
                const int xx = xbase + e;
                if (xx >= 0 && xx < TPX)
                    *(uint4v*)&sx[(y * TPX + xx) * CSH + cg8 * 8] = pk;
                if (xlo && gxe == 1)
                    *(uint4v*)&sx[(y * TPX + 0) * CSH + cg8 * 8] = pk;
                if (xhi && gxe == 126)
                    *(uint4v*)&sx[(y * TPX + 17) * CSH + cg8 * 8] = pk;
            }
        }
    }
    __syncthreads();

    const bool border = (bx == 0) | (bx == 7) | (by == 0) | (by == 15);
    const int n = fm;

    // ---- per row: conv MFMA -> softmax -> mask broadcast -> carafe from regs
    for (int rr = 0; rr < 4; ++rr) {
        const int R = wv * 4 + rr;
        const int h = ty0 + R, w = tx0 + n;

        short8 bfr[18];
#pragma unroll
        for (int s = 0; s < 18; ++s) {
            const int tap = s >> 1;
            const int dy = tap / 3 - 1, dx = tap % 3 - 1;
            bfr[s] = *(const short8*)&sx[((R + 1 + dy) * TPX + (n + 1 + dx)) * CSH
                                         + (s & 1) * 32 + fq * 8];
        }

        floatx4 acc = {0.f, 0.f, 0.f, 0.f};
        if (border) {
#pragma unroll
            for (int s = 0; s < 18; ++s) {
                const int tap = s >> 1;
                const int dy = tap / 3 - 1, dx = tap % 3 - 1;
                const int hy = h + dy, wx = w + dx;
                short8 bb = bfr[s];
                if (hy < 0 || hy >= IH || wx < 0 || wx >= IW) bb = (short8)0;
                acc = __builtin_amdgcn_mfma_f32_16x16x32_bf16(afr[s], bb, acc, 0, 0, 0);
            }
        } else {
#pragma unroll
            for (int s = 0; s < 18; ++s)
                acc = __builtin_amdgcn_mfma_f32_16x16x32_bf16(afr[s], bfr[s], acc, 0, 0, 0);
        }

        // softmax*hamming, denom-cancelled; lane holds taps fq*4+r of pixel n
        auto hamt = [](int t) {
            const float a = (t / 3 == 1) ? 1.f : 0.08f;
            const float b = (t % 3 == 1) ? 1.f : 0.08f;
            return a * b;
        };
        const int nval = (fq < 2) ? 4 : (fq == 2 ? 1 : 0);
        float e0 = 0, e1 = 0, e2 = 0, e3 = 0, ssum = 0;
        if (nval >= 1) { e0 = __expf(acc[0] + bq[0]) * hamt(fq * 4 + 0); ssum += e0; }
        if (nval >= 4) { e1 = __expf(acc[1] + bq[1]) * hamt(fq * 4 + 1); ssum += e1;
                         e2 = __expf(acc[2] + bq[2]) * hamt(fq * 4 + 2); ssum += e2;
                         e3 = __expf(acc[3] + bq[3]) * hamt(fq * 4 + 3); ssum += e3; }
        ssum += __shfl_xor(ssum, 16);
        ssum += __shfl_xor(ssum, 32);
        const float inv = 1.0f / ssum;

        // broadcast 9 taps to every lane of pixel n (bf16-packed, 5 shuffles)
        const unsigned p01 = cvtpk(e0 * inv, e1 * inv);
        const unsigned p23 = cvtpk(e2 * inv, e3 * inv);
        const unsigned q0 = (unsigned)__shfl((int)p01, n);
        const unsigned q1 = (unsigned)__shfl((int)p23, n);
        const unsigned q2 = (unsigned)__shfl((int)p01, 16 + n);
        const unsigned q3 = (unsigned)__shfl((int)p23, 16 + n);
        const unsigned q4 = (unsigned)__shfl((int)p01, 32 + n);
        float mk[9];
        { float2v m;
          m = unpk(q0); mk[0] = m.x; mk[1] = m.y;
          m = unpk(q1); mk[2] = m.x; mk[3] = m.y;
          m = unpk(q2); mk[4] = m.x; mk[5] = m.y;
          m = unpk(q3); mk[6] = m.x; mk[7] = m.y;
          mk[8] = unpk(q4).x; }

        // carafe from registers: lane covers ch {8fq..}+{32+8fq..} of pixel n
        float2v l[8];
#pragma unroll
        for (int q = 0; q < 8; ++q) l[q] = (float2v)0.f;
#pragma unroll
        for (int t = 0; t < 9; ++t) {
            const float mt = mk[t];
            const uint4v b0 = *(const uint4v*)&bfr[2 * t];
            const uint4v b1 = *(const uint4v*)&bfr[2 * t + 1];
#pragma unroll
            for (int q = 0; q < 4; ++q) {
                l[q]     += mt * unpk(b0[q]);
                l[q + 4] += mt * unpk(b1[q]);
            }
        }
        const uint4v c0 = *(const uint4v*)&bfr[8];
        const uint4v c1 = *(const uint4v*)&bfr[9];
        float* ob = out + (size_t)bz * CCH * hw + (size_t)h * IW + w
                  + (size_t)(8 * fq) * hw;
#pragma unroll
        for (int q = 0; q < 4; ++q) {
            const float2v oe = 2.f * unpk(c0[q]) - l[q];
            const float2v oo = 2.f * unpk(c1[q]) - l[q + 4];
            ob[(size_t)(2 * q) * hw]          = oe.x;
            ob[(size_t)(2 * q + 1) * hw]      = oe.y;
            ob[(size_t)(32 + 2 * q) * hw]     = oo.x;
            ob[(size_t)(32 + 2 * q + 1) * hw] = oo.y;
        }
    }
}

extern "C" void kernel_launch(void* const* d_in, const int* in_sizes, int n_in,
                              void* d_out, int out_size, void* d_ws, size_t ws_size,
                              hipStream_t stream) {
    const float* x    = (const float*)d_in[0];
    const float* Wg   = (const float*)d_in[1];
    const float* bias = (const float*)d_in[2];
    float* out        = (float*)d_out;
    const int B = in_sizes[0] / (CCH * IH * IW);
    dim3 grid(8, 16, B);

    if (ws_size >= 18 * 64 * 16) {
        unsigned short* wsp = (unsigned short*)d_ws;
        ahpf_prep<<<5, 256, 0, stream>>>(Wg, wsp);
        ahpf_kernel<true><<<grid, dim3(128, 1, 1), 0, stream>>>(x, Wg, bias, out, wsp);
    } else {
        ahpf_kernel<false><<<grid, dim3(128, 1, 1), 0, stream>>>(x, Wg, bias, out, nullptr);
    }
}

// Round 2
// 99.297 us; speedup vs baseline: 1.0489x; 1.0080x over previous
//
#include <hip/hip_runtime.h>

// AdaptiveHighPassFilter: conv3x3(64->9, zero-pad) -> softmax(taps) -> hamming
// renorm -> CARAFE(3x3, reflect) -> 2x - lowpass.
//
// R8 = R7 + two structural cuts in the per-row loop:
//  (a) carafe via v_dot2_f32_bf16: masks are already bf16 tap-pairs
//      (q0..q4); pair x across taps with v_perm_b32 (1 inst) and accumulate
//      2 taps/channel per dot2. 160 ops/row vs ~290-430 unpk+fma. Mask
//      unpack (mk[9]) eliminated. Epilogue 2x-l unchanged (same numerics).
//  (b) bfr rotation: rows share 12/18 fragments (dy=0,+1 -> dy=-1,0); rr
//      loop fully unrolled, rotate registers, load only 6 new ds_read_b128
//      per row after the first. 36 instead of 72 ds_reads/thread.
// R7: cvt_pk_bf16_f32 staging pack. R5/R6 design: carafe from conv's own
// B-fragments, mask broadcast via 5 shuffles, one barrier; weights
// pre-fragmented via prep kernel; 16x8 tiles, 128 thr, XCD swizzle.

typedef __attribute__((ext_vector_type(8))) short short8;
typedef __attribute__((ext_vector_type(4))) float floatx4;
typedef __attribute__((ext_vector_type(4))) unsigned uint4v;
typedef __attribute__((ext_vector_type(2))) float float2v;

#define IH 128
#define IW 128
#define CCH 64
#define TSX 16
#define TSY 8
#define TPX 18
#define TPY 10
#define CSH 72   // shorts per position: 144B row, 16B-aligned, bank stride 4

#define SELLO 0x05040100u
#define SELHI 0x07060302u

__device__ __forceinline__ unsigned short f2bf(float f) {
    unsigned u = __float_as_uint(f);
    u += 0x7FFFu + ((u >> 16) & 1u);     // round-to-nearest-even
    return (unsigned short)(u >> 16);
}
// 1-instruction RNE pack of two f32 -> packed bf16x2 (lo = a, hi = b)
__device__ __forceinline__ unsigned cvtpk(float a, float b) {
    unsigned r;
    asm("v_cvt_pk_bf16_f32 %0, %1, %2" : "=v"(r) : "v"(a), "v"(b));
    return r;
}
__device__ __forceinline__ float2v unpk(unsigned u) {
    float2v r;
    r.x = __uint_as_float(u << 16);
    r.y = __uint_as_float(u & 0xFFFF0000u);
    return r;
}
// byte-permute: pool = {hi (bytes 4-7), lo (bytes 0-3)}
__device__ __forceinline__ unsigned permb(unsigned hi, unsigned lo, unsigned sel) {
    unsigned d;
    asm("v_perm_b32 %0, %1, %2, %3" : "=v"(d) : "v"(hi), "v"(lo), "s"(sel));
    return d;
}
// acc += x2.lo*m2.lo + x2.hi*m2.hi   (bf16 inputs, f32 accum)
__device__ __forceinline__ float dot2bf(unsigned x2, unsigned m2, float acc) {
    asm("v_dot2_f32_bf16 %0, %1, %2, %0" : "+v"(acc) : "v"(x2), "v"(m2));
    return acc;
}

// ---- prep: W[9][64][3][3] f32 -> bf16 A-fragments ws[s][lane][8shorts]
__global__ void ahpf_prep(const float* __restrict__ Wg,
                          unsigned short* __restrict__ wsp)
{
    const int i = blockIdx.x * 256 + threadIdx.x;   // 0..1151
    if (i >= 18 * 64) return;
    const int s = i >> 6, l = i & 63;
    const int fm = l & 15, fq = l >> 4;
    const int tap = s >> 1, cb = (s & 1) * 32 + fq * 8;
    short8 v = (short8)0;
    if (fm < 9) {
#pragma unroll
        for (int jj = 0; jj < 8; ++jj)
            v[jj] = (short)f2bf(Wg[fm * 576 + (cb + jj) * 9 + tap]);
    }
    ((short8*)wsp)[i] = v;
}

template <bool USE_WS>
__global__ __launch_bounds__(128, 2) void ahpf_kernel(
    const float* __restrict__ x, const float* __restrict__ Wg,
    const float* __restrict__ bias, float* __restrict__ out,
    const unsigned short* __restrict__ wsp)
{
    __shared__ __align__(16) unsigned short sx[TPY * TPX * CSH];  // 25,920 B

    const int tid  = threadIdx.x;
    const int lane = tid & 63;
    const int wv   = tid >> 6;

    // XCD swizzle: XCD k gets the 128 tiles of image k
    const unsigned flat = blockIdx.x + 8u * (blockIdx.y + 16u * blockIdx.z);
    const unsigned nid  = (flat & 7u) * 128u + (flat >> 3);
    const int bx = nid & 7, by = (nid >> 3) & 15, bz = nid >> 7;

    const int ty0 = by * TSY;
    const int tx0 = bx * TSX;
    const size_t hw = (size_t)IH * IW;
    const float* xb = x + (size_t)bz * CCH * hw;

    const int fm = lane & 15;   // conv: pixel col n / A row m
    const int fq = lane >> 4;

    // ---- A-fragments: 18 coalesced b128 loads from prep ws (or gather fallback)
    short8 afr[18];
    if (USE_WS) {
        const short8* wf = (const short8*)wsp;
#pragma unroll
        for (int s = 0; s < 18; ++s) afr[s] = wf[s * 64 + lane];
    } else {
#pragma unroll
        for (int s = 0; s < 18; ++s) {
            short8 a = (short8)0;
            if (fm < 9) {
                const int tap = s >> 1, cb = (s & 1) * 32 + fq * 8;
                const float* wp = Wg + fm * 576 + tap;
#pragma unroll
                for (int jj = 0; jj < 8; ++jj)
                    a[jj] = (short)f2bf(wp[(cb + jj) * 9]);
            }
            afr[s] = a;
        }
    }
    float bq[4];
#pragma unroll
    for (int r = 0; r < 4; ++r) {
        const int t = fq * 4 + r;
        bq[r] = (t < 9) ? bias[t] : 0.0f;
    }

    // ---- stage reflect-padded tile bf16 [pos][c]; slots = 8ch x 4pos
    {
        int gx0 = tx0 - 4;
        if (gx0 < 0) gx0 = 0;
        if (gx0 > IW - 24) gx0 = IW - 24;
        const bool xlo = (bx == 0), xhi = (bx == 7);
        const int cg8 = tid & 7;                 // fixed per thread
#pragma unroll
        for (int it = 0; it < 4; ++it) {
            const int s = it * 128 + tid;        // 480 slots total
            if (s >= 480) break;
            const int u = s >> 3;                // 0..59
            const int y = u / 6, xg = u - 6 * y;
            int gy = ty0 + y - 1;
            gy = gy < 0 ? -gy : (gy >= IH ? 2 * IH - 2 - gy : gy);
            const float* src = xb + (size_t)(cg8 * 8) * hw
                             + (size_t)gy * IW + gx0 + 4 * xg;
            float4 v[8];
#pragma unroll
            for (int jj = 0; jj < 8; ++jj)
                v[jj] = *(const float4*)(src + (size_t)jj * hw);
            const int xbase = gx0 + 4 * xg - tx0 + 1;
#pragma unroll
            for (int e = 0; e < 4; ++e) {
                const float fe[8] = {
                    ((const float*)&v[0])[e], ((const float*)&v[1])[e],
                    ((const float*)&v[2])[e], ((const float*)&v[3])[e],
                    ((const float*)&v[4])[e], ((const float*)&v[5])[e],
                    ((const float*)&v[6])[e], ((const float*)&v[7])[e]};
                uint4v pk;
                pk.x = cvtpk(fe[0], fe[1]); pk.y = cvtpk(fe[2], fe[3]);
                pk.z = cvtpk(fe[4], fe[5]); pk.w = cvtpk(fe[6], fe[7]);
                const int gxe = gx0 + 4 * xg + e;
                const int xx = xbase + e;
                if (xx >= 0 && xx < TPX)
                    *(uint4v*)&sx[(y * TPX + xx) * CSH + cg8 * 8] = pk;
                if (xlo && gxe == 1)
                    *(uint4v*)&sx[(y * TPX + 0) * CSH + cg8 * 8] = pk;
                if (xhi && gxe == 126)
                    *(uint4v*)&sx[(y * TPX + 17) * CSH + cg8 * 8] = pk;
            }
        }
    }
    __syncthreads();

    const bool border = (bx == 0) | (bx == 7) | (by == 0) | (by == 15);
    const int n = fm;

    // carafe tap-pair accumulation: 2 perm + 2 dot2 per (2ch x 2taps)
#define CARAFE_PAIR(sa, sb, qq)                                              \
    {                                                                        \
        const uint4v A0 = *(const uint4v*)&bfr[(sa)];                        \
        const uint4v B0 = *(const uint4v*)&bfr[(sb)];                        \
        const uint4v A1 = *(const uint4v*)&bfr[(sa) + 1];                    \
        const uint4v B1 = *(const uint4v*)&bfr[(sb) + 1];                    \
        _Pragma("unroll")                                                    \
        for (int u = 0; u < 4; ++u) {                                        \
            l[2*u]       = dot2bf(permb(B0[u], A0[u], SELLO), qq, l[2*u]);   \
            l[2*u + 1]   = dot2bf(permb(B0[u], A0[u], SELHI), qq, l[2*u+1]); \
            l[8 + 2*u]   = dot2bf(permb(B1[u], A1[u], SELLO), qq, l[8+2*u]); \
            l[8 + 2*u+1] = dot2bf(permb(B1[u], A1[u], SELHI), qq, l[8+2*u+1]);\
        }                                                                    \
    }

    // ---- per row: conv MFMA -> softmax -> mask broadcast -> carafe (dot2)
    short8 bfr[18];
#pragma unroll
    for (int rr = 0; rr < 4; ++rr) {
        const int R = wv * 4 + rr;
        const int h = ty0 + R, w = tx0 + n;

        if (rr == 0) {
#pragma unroll
            for (int s = 0; s < 18; ++s) {
                const int tap = s >> 1;
                const int dy = tap / 3 - 1, dx = tap % 3 - 1;
                bfr[s] = *(const short8*)&sx[((R + 1 + dy) * TPX + (n + 1 + dx)) * CSH
                                             + (s & 1) * 32 + fq * 8];
            }
        } else {
            // rows share dy=0,+1 of prev = dy=-1,0 of current: rotate by 6
#pragma unroll
            for (int s = 0; s < 12; ++s) bfr[s] = bfr[s + 6];
#pragma unroll
            for (int s = 12; s < 18; ++s) {
                const int dx = (s >> 1) % 3 - 1;
                bfr[s] = *(const short8*)&sx[((R + 2) * TPX + (n + 1 + dx)) * CSH
                                             + (s & 1) * 32 + fq * 8];
            }
        }

        floatx4 acc = {0.f, 0.f, 0.f, 0.f};
        if (border) {
#pragma unroll
            for (int s = 0; s < 18; ++s) {
                const int tap = s >> 1;
                const int dy = tap / 3 - 1, dx = tap % 3 - 1;
                const int hy = h + dy, wx = w + dx;
                short8 bb = bfr[s];
                if (hy < 0 || hy >= IH || wx < 0 || wx >= IW) bb = (short8)0;
                acc = __builtin_amdgcn_mfma_f32_16x16x32_bf16(afr[s], bb, acc, 0, 0, 0);
            }
        } else {
#pragma unroll
            for (int s = 0; s < 18; ++s)
                acc = __builtin_amdgcn_mfma_f32_16x16x32_bf16(afr[s], bfr[s], acc, 0, 0, 0);
        }

        // softmax*hamming, denom-cancelled; lane holds taps fq*4+r of pixel n
        auto hamt = [](int t) {
            const float a = (t / 3 == 1) ? 1.f : 0.08f;
            const float b = (t % 3 == 1) ? 1.f : 0.08f;
            return a * b;
        };
        const int nval = (fq < 2) ? 4 : (fq == 2 ? 1 : 0);
        float e0 = 0, e1 = 0, e2 = 0, e3 = 0, ssum = 0;
        if (nval >= 1) { e0 = __expf(acc[0] + bq[0]) * hamt(fq * 4 + 0); ssum += e0; }
        if (nval >= 4) { e1 = __expf(acc[1] + bq[1]) * hamt(fq * 4 + 1); ssum += e1;
                         e2 = __expf(acc[2] + bq[2]) * hamt(fq * 4 + 2); ssum += e2;
                         e3 = __expf(acc[3] + bq[3]) * hamt(fq * 4 + 3); ssum += e3; }
        ssum += __shfl_xor(ssum, 16);
        ssum += __shfl_xor(ssum, 32);
        const float inv = 1.0f / ssum;

        // broadcast 9 taps to every lane of pixel n as bf16 TAP-PAIRS:
        // q0=(m0,m1) q1=(m2,m3) q2=(m4,m5) q3=(m6,m7) q4=(m8,0)
        const unsigned p01 = cvtpk(e0 * inv, e1 * inv);
        const unsigned p23 = cvtpk(e2 * inv, e3 * inv);
        const unsigned q0 = (unsigned)__shfl((int)p01, n);
        const unsigned q1 = (unsigned)__shfl((int)p23, n);
        const unsigned q2 = (unsigned)__shfl((int)p01, 16 + n);
        const unsigned q3 = (unsigned)__shfl((int)p23, 16 + n);
        const unsigned q4 = (unsigned)__shfl((int)p01, 32 + n);

        // carafe from registers via bf16 dot2: lane covers ch {8fq..}+{32+8fq..}
        float l[16];
#pragma unroll
        for (int i = 0; i < 16; ++i) l[i] = 0.f;
        CARAFE_PAIR(0,  2,  q0);   // taps 0,1
        CARAFE_PAIR(4,  6,  q1);   // taps 2,3
        CARAFE_PAIR(8,  10, q2);   // taps 4,5
        CARAFE_PAIR(12, 14, q3);   // taps 6,7
        CARAFE_PAIR(16, 16, q4);   // tap 8 (hi mask = 0)

        const uint4v c0 = *(const uint4v*)&bfr[8];   // center tap (t=4)
        const uint4v c1 = *(const uint4v*)&bfr[9];
        float* ob = out + (size_t)bz * CCH * hw + (size_t)h * IW + w
                  + (size_t)(8 * fq) * hw;
#pragma unroll
        for (int q = 0; q < 4; ++q) {
            const float2v ce = unpk(c0[q]);
            const float2v co = unpk(c1[q]);
            ob[(size_t)(2 * q) * hw]          = 2.f * ce.x - l[2 * q];
            ob[(size_t)(2 * q + 1) * hw]      = 2.f * ce.y - l[2 * q + 1];
            ob[(size_t)(32 + 2 * q) * hw]     = 2.f * co.x - l[8 + 2 * q];
            ob[(size_t)(32 + 2 * q + 1) * hw] = 2.f * co.y - l[8 + 2 * q + 1];
        }
    }
#undef CARAFE_PAIR
}

extern "C" void kernel_launch(void* const* d_in, const int* in_sizes, int n_in,
                              void* d_out, int out_size, void* d_ws, size_t ws_size,
                              hipStream_t stream) {
    const float* x    = (const float*)d_in[0];
    const float* Wg   = (const float*)d_in[1];
    const float* bias = (const float*)d_in[2];
    float* out        = (float*)d_out;
    const int B = in_sizes[0] / (CCH * IH * IW);
    dim3 grid(8, 16, B);

    if (ws_size >= 18 * 64 * 16) {
        unsigned short* wsp = (unsigned short*)d_ws;
        ahpf_prep<<<5, 256, 0, stream>>>(Wg, wsp);
        ahpf_kernel<true><<<grid, dim3(128, 1, 1), 0, stream>>>(x, Wg, bias, out, wsp);
    } else {
        ahpf_kernel<false><<<grid, dim3(128, 1, 1), 0, stream>>>(x, Wg, bias, out, nullptr);
    }
}

// Round 3
// 97.687 us; speedup vs baseline: 1.0662x; 1.0165x over previous
//
#include <hip/hip_runtime.h>
#include <hip/hip_fp16.h>

// AdaptiveHighPassFilter: conv3x3(64->9, zero-pad) -> softmax(taps) -> hamming
// renorm -> CARAFE(3x3, reflect) -> 2x - lowpass.
//
// R9 = R8 switched from bf16 to fp16 end-to-end:
//  (a) carafe via v_pk_fma_f16 with op_sel mask-half broadcast: x fragments
//      are channel-pairs, mask word (m_t,m_t+1) half-broadcast by op_sel ->
//      2 products/inst, zero operand prep. 72 inst/row vs 160 (perm+dot2).
//  (b) epilogue 2x-l as one v_pk_fma_f16 (neg_lo/neg_hi on l) per channel
//      pair, then cvt to f32 for stores. l accum is f16 pairs (8 VGPRs).
//  (c) conv MFMA -> mfma_f32_16x16x32_f16 (same shape/rate as bf16);
//      staging pack -> v_cvt_pkrtz_f16_f32; prep weights -> fp16.
//  fp16 (10-bit mantissa) is strictly more precise than bf16 (8-bit) at
//  these magnitudes (|x|<~6, logits <1), so absmax should hold or improve.
// Evidence trail: R7 (-4.1us, cvt_pk pack) and R8 (-0.8us, dot2+rotation)
// show main kernel ~11us VALU-bound; ~85us of dur_us is harness poison
// fills (2x 42.5us, 268MB each) we cannot touch.

typedef __attribute__((ext_vector_type(8))) short short8;
typedef __attribute__((ext_vector_type(4))) float floatx4;
typedef __attribute__((ext_vector_type(4))) unsigned uint4v;

#define IH 128
#define IW 128
#define CCH 64
#define TSX 16
#define TSY 8
#define TPX 18
#define TPY 10
#define CSH 72   // shorts per position: 144B row, 16B-aligned, bank stride 4

// 1-instruction pack of two f32 -> packed f16x2 (lo = a, hi = b), RTZ
__device__ __forceinline__ unsigned cvtpkh(float a, float b) {
    unsigned r;
    asm("v_cvt_pkrtz_f16_f32 %0, %1, %2" : "=v"(r) : "v"(a), "v"(b));
    return r;
}
// l_pair += x_pair * m.lo   (f16 packed, mask lo-half broadcast via op_sel)
__device__ __forceinline__ unsigned pkfma_lo(unsigned x2, unsigned m2, unsigned acc) {
    unsigned d;
    asm("v_pk_fma_f16 %0, %1, %2, %3 op_sel:[0,0,0] op_sel_hi:[1,0,1]"
        : "=v"(d) : "v"(x2), "v"(m2), "v"(acc));
    return d;
}
// l_pair += x_pair * m.hi
__device__ __forceinline__ unsigned pkfma_hi(unsigned x2, unsigned m2, unsigned acc) {
    unsigned d;
    asm("v_pk_fma_f16 %0, %1, %2, %3 op_sel:[0,1,0] op_sel_hi:[1,1,1]"
        : "=v"(d) : "v"(x2), "v"(m2), "v"(acc));
    return d;
}
// o_pair = c_pair * 2.0 - l_pair   (f16 packed)
__device__ __forceinline__ unsigned pk2xml(unsigned c2, unsigned two2, unsigned l2) {
    unsigned d;
    asm("v_pk_fma_f16 %0, %1, %2, %3 neg_lo:[0,0,1] neg_hi:[0,0,1]"
        : "=v"(d) : "v"(c2), "v"(two2), "v"(l2));
    return d;
}
__device__ __forceinline__ float h2f_lo(unsigned u) {
    return __half2float(__ushort_as_half((unsigned short)(u & 0xFFFFu)));
}
__device__ __forceinline__ float h2f_hi(unsigned u) {
    return __half2float(__ushort_as_half((unsigned short)(u >> 16)));
}
__device__ __forceinline__ unsigned short f2h(float f) {
    return __half_as_ushort(__float2half(f));   // RNE
}

// ---- prep: W[9][64][3][3] f32 -> fp16 A-fragments ws[s][lane][8shorts]
__global__ void ahpf_prep(const float* __restrict__ Wg,
                          unsigned short* __restrict__ wsp)
{
    const int i = blockIdx.x * 256 + threadIdx.x;   // 0..1151
    if (i >= 18 * 64) return;
    const int s = i >> 6, l = i & 63;
    const int fm = l & 15, fq = l >> 4;
    const int tap = s >> 1, cb = (s & 1) * 32 + fq * 8;
    short8 v = (short8)0;
    if (fm < 9) {
#pragma unroll
        for (int jj = 0; jj < 8; ++jj)
            v[jj] = (short)f2h(Wg[fm * 576 + (cb + jj) * 9 + tap]);
    }
    ((short8*)wsp)[i] = v;
}

template <bool USE_WS>
__global__ __launch_bounds__(128, 2) void ahpf_kernel(
    const float* __restrict__ x, const float* __restrict__ Wg,
    const float* __restrict__ bias, float* __restrict__ out,
    const unsigned short* __restrict__ wsp)
{
    __shared__ __align__(16) unsigned short sx[TPY * TPX * CSH];  // 25,920 B

    const int tid  = threadIdx.x;
    const int lane = tid & 63;
    const int wv   = tid >> 6;

    // XCD swizzle: XCD k gets the 128 tiles of image k
    const unsigned flat = blockIdx.x + 8u * (blockIdx.y + 16u * blockIdx.z);
    const unsigned nid  = (flat & 7u) * 128u + (flat >> 3);
    const int bx = nid & 7, by = (nid >> 3) & 15, bz = nid >> 7;

    const int ty0 = by * TSY;
    const int tx0 = bx * TSX;
    const size_t hw = (size_t)IH * IW;
    const float* xb = x + (size_t)bz * CCH * hw;

    const int fm = lane & 15;   // conv: pixel col n / A row m
    const int fq = lane >> 4;

    // ---- A-fragments: 18 coalesced b128 loads from prep ws (or gather fallback)
    short8 afr[18];
    if (USE_WS) {
        const short8* wf = (const short8*)wsp;
#pragma unroll
        for (int s = 0; s < 18; ++s) afr[s] = wf[s * 64 + lane];
    } else {
#pragma unroll
        for (int s = 0; s < 18; ++s) {
            short8 a = (short8)0;
            if (fm < 9) {
                const int tap = s >> 1, cb = (s & 1) * 32 + fq * 8;
                const float* wp = Wg + fm * 576 + tap;
#pragma unroll
                for (int jj = 0; jj < 8; ++jj)
                    a[jj] = (short)f2h(wp[(cb + jj) * 9]);
            }
            afr[s] = a;
        }
    }
    float bq[4];
#pragma unroll
    for (int r = 0; r < 4; ++r) {
        const int t = fq * 4 + r;
        bq[r] = (t < 9) ? bias[t] : 0.0f;
    }

    // ---- stage reflect-padded tile fp16 [pos][c]; slots = 8ch x 4pos
    {
        int gx0 = tx0 - 4;
        if (gx0 < 0) gx0 = 0;
        if (gx0 > IW - 24) gx0 = IW - 24;
        const bool xlo = (bx == 0), xhi = (bx == 7);
        const int cg8 = tid & 7;                 // fixed per thread
#pragma unroll
        for (int it = 0; it < 4; ++it) {
            const int s = it * 128 + tid;        // 480 slots total
            if (s >= 480) break;
            const int u = s >> 3;                // 0..59
            const int y = u / 6, xg = u - 6 * y;
            int gy = ty0 + y - 1;
            gy = gy < 0 ? -gy : (gy >= IH ? 2 * IH - 2 - gy : gy);
            const float* src = xb + (size_t)(cg8 * 8) * hw
                             + (size_t)gy * IW + gx0 + 4 * xg;
            float4 v[8];
#pragma unroll
            for (int jj = 0; jj < 8; ++jj)
                v[jj] = *(const float4*)(src + (size_t)jj * hw);
            const int xbase = gx0 + 4 * xg - tx0 + 1;
#pragma unroll
            for (int e = 0; e < 4; ++e) {
                const float fe[8] = {
                    ((const float*)&v[0])[e], ((const float*)&v[1])[e],
                    ((const float*)&v[2])[e], ((const float*)&v[3])[e],
                    ((const float*)&v[4])[e], ((const float*)&v[5])[e],
                    ((const float*)&v[6])[e], ((const float*)&v[7])[e]};
                uint4v pk;
                pk.x = cvtpkh(fe[0], fe[1]); pk.y = cvtpkh(fe[2], fe[3]);
                pk.z = cvtpkh(fe[4], fe[5]); pk.w = cvtpkh(fe[6], fe[7]);
                const int gxe = gx0 + 4 * xg + e;
                const int xx = xbase + e;
                if (xx >= 0 && xx < TPX)
                    *(uint4v*)&sx[(y * TPX + xx) * CSH + cg8 * 8] = pk;
                if (xlo && gxe == 1)
                    *(uint4v*)&sx[(y * TPX + 0) * CSH + cg8 * 8] = pk;
                if (xhi && gxe == 126)
                    *(uint4v*)&sx[(y * TPX + 17) * CSH + cg8 * 8] = pk;
            }
        }
    }
    __syncthreads();

    const bool border = (bx == 0) | (bx == 7) | (by == 0) | (by == 15);
    const int n = fm;

    // carafe: one tap, 16 channels = 8 pk_fma (mask half broadcast by op_sel)
#define CARAFE_TAP(t, qq, HALF)                                              \
    {                                                                        \
        const uint4v A = *(const uint4v*)&bfr[2 * (t)];                      \
        const uint4v Bv = *(const uint4v*)&bfr[2 * (t) + 1];                 \
        _Pragma("unroll")                                                    \
        for (int u = 0; u < 4; ++u) {                                        \
            l[u]     = pkfma_##HALF(A[u],  qq, l[u]);                        \
            l[4 + u] = pkfma_##HALF(Bv[u], qq, l[4 + u]);                    \
        }                                                                    \
    }

    // ---- per row: conv MFMA -> softmax -> mask broadcast -> carafe (pk_fma)
    short8 bfr[18];
#pragma unroll
    for (int rr = 0; rr < 4; ++rr) {
        const int R = wv * 4 + rr;
        const int h = ty0 + R, w = tx0 + n;

        if (rr == 0) {
#pragma unroll
            for (int s = 0; s < 18; ++s) {
                const int tap = s >> 1;
                const int dy = tap / 3 - 1, dx = tap % 3 - 1;
                bfr[s] = *(const short8*)&sx[((R + 1 + dy) * TPX + (n + 1 + dx)) * CSH
                                             + (s & 1) * 32 + fq * 8];
            }
        } else {
            // rows share dy=0,+1 of prev = dy=-1,0 of current: rotate by 6
#pragma unroll
            for (int s = 0; s < 12; ++s) bfr[s] = bfr[s + 6];
#pragma unroll
            for (int s = 12; s < 18; ++s) {
                const int dx = (s >> 1) % 3 - 1;
                bfr[s] = *(const short8*)&sx[((R + 2) * TPX + (n + 1 + dx)) * CSH
                                             + (s & 1) * 32 + fq * 8];
            }
        }

        floatx4 acc = {0.f, 0.f, 0.f, 0.f};
        if (border) {
#pragma unroll
            for (int s = 0; s < 18; ++s) {
                const int tap = s >> 1;
                const int dy = tap / 3 - 1, dx = tap % 3 - 1;
                const int hy = h + dy, wx = w + dx;
                short8 bb = bfr[s];
                if (hy < 0 || hy >= IH || wx < 0 || wx >= IW) bb = (short8)0;
                acc = __builtin_amdgcn_mfma_f32_16x16x32_f16(afr[s], bb, acc, 0, 0, 0);
            }
        } else {
#pragma unroll
            for (int s = 0; s < 18; ++s)
                acc = __builtin_amdgcn_mfma_f32_16x16x32_f16(afr[s], bfr[s], acc, 0, 0, 0);
        }

        // softmax*hamming, denom-cancelled; lane holds taps fq*4+r of pixel n
        auto hamt = [](int t) {
            const float a = (t / 3 == 1) ? 1.f : 0.08f;
            const float b = (t % 3 == 1) ? 1.f : 0.08f;
            return a * b;
        };
        const int nval = (fq < 2) ? 4 : (fq == 2 ? 1 : 0);
        float e0 = 0, e1 = 0, e2 = 0, e3 = 0, ssum = 0;
        if (nval >= 1) { e0 = __expf(acc[0] + bq[0]) * hamt(fq * 4 + 0); ssum += e0; }
        if (nval >= 4) { e1 = __expf(acc[1] + bq[1]) * hamt(fq * 4 + 1); ssum += e1;
                         e2 = __expf(acc[2] + bq[2]) * hamt(fq * 4 + 2); ssum += e2;
                         e3 = __expf(acc[3] + bq[3]) * hamt(fq * 4 + 3); ssum += e3; }
        ssum += __shfl_xor(ssum, 16);
        ssum += __shfl_xor(ssum, 32);
        const float inv = 1.0f / ssum;

        // broadcast 9 taps to every lane of pixel n as f16 TAP-PAIRS:
        // q0=(m0,m1) q1=(m2,m3) q2=(m4,m5) q3=(m6,m7) q4=(m8,0)
        const unsigned p01 = cvtpkh(e0 * inv, e1 * inv);
        const unsigned p23 = cvtpkh(e2 * inv, e3 * inv);
        const unsigned q0 = (unsigned)__shfl((int)p01, n);
        const unsigned q1 = (unsigned)__shfl((int)p23, n);
        const unsigned q2 = (unsigned)__shfl((int)p01, 16 + n);
        const unsigned q3 = (unsigned)__shfl((int)p23, 16 + n);
        const unsigned q4 = (unsigned)__shfl((int)p01, 32 + n);

        // carafe from registers via packed f16 fma: ch {8fq..}+{32+8fq..}
        unsigned l[8];
#pragma unroll
        for (int i = 0; i < 8; ++i) l[i] = 0u;
        CARAFE_TAP(0, q0, lo);
        CARAFE_TAP(1, q0, hi);
        CARAFE_TAP(2, q1, lo);
        CARAFE_TAP(3, q1, hi);
        CARAFE_TAP(4, q2, lo);
        CARAFE_TAP(5, q2, hi);
        CARAFE_TAP(6, q3, lo);
        CARAFE_TAP(7, q3, hi);
        CARAFE_TAP(8, q4, lo);

        const uint4v c0 = *(const uint4v*)&bfr[8];   // center tap (t=4)
        const uint4v c1 = *(const uint4v*)&bfr[9];
        const unsigned TWO2 = 0x40004000u;           // (2.0h, 2.0h)
        float* ob = out + (size_t)bz * CCH * hw + (size_t)h * IW + w
                  + (size_t)(8 * fq) * hw;
#pragma unroll
        for (int q = 0; q < 4; ++q) {
            const unsigned oe = pk2xml(c0[q], TWO2, l[q]);
            const unsigned oo = pk2xml(c1[q], TWO2, l[4 + q]);
            ob[(size_t)(2 * q) * hw]          = h2f_lo(oe);
            ob[(size_t)(2 * q + 1) * hw]      = h2f_hi(oe);
            ob[(size_t)(32 + 2 * q) * hw]     = h2f_lo(oo);
            ob[(size_t)(32 + 2 * q + 1) * hw] = h2f_hi(oo);
        }
    }
#undef CARAFE_TAP
}

extern "C" void kernel_launch(void* const* d_in, const int* in_sizes, int n_in,
                              void* d_out, int out_size, void* d_ws, size_t ws_size,
                              hipStream_t stream) {
    const float* x    = (const float*)d_in[0];
    const float* Wg   = (const float*)d_in[1];
    const float* bias = (const float*)d_in[2];
    float* out        = (float*)d_out;
    const int B = in_sizes[0] / (CCH * IH * IW);
    dim3 grid(8, 16, B);

    if (ws_size >= 18 * 64 * 16) {
        unsigned short* wsp = (unsigned short*)d_ws;
        ahpf_prep<<<5, 256, 0, stream>>>(Wg, wsp);
        ahpf_kernel<true><<<grid, dim3(128, 1, 1), 0, stream>>>(x, Wg, bias, out, wsp);
    } else {
        ahpf_kernel<false><<<grid, dim3(128, 1, 1), 0, stream>>>(x, Wg, bias, out, nullptr);
    }
}